// Round 2
// baseline (672.388 us; speedup 1.0000x reference)
//
#include <hip/hip_runtime.h>
#include <hip/hip_bf16.h>

#define N_BATCH 128
#define T_STEPS 512
#define F_IN 3
#define H_DIM 5
#define NEURONS 2000
#define NT (N_BATCH * T_STEPS)

__device__ __forceinline__ float fast_rcp(float x) {
    return __builtin_amdgcn_rcpf(x);
}

__device__ __forceinline__ float fast_sigmoid(float x) {
    // 1 / (1 + exp(-x)); v_exp_f32 is ~1-2 ulp
    return fast_rcp(1.0f + __expf(-x));
}

__device__ __forceinline__ float fast_tanh(float x) {
    // tanh(x) = (e^{2x} - 1) / (e^{2x} + 1)
    float t = __expf(x + x);
    return (t - 1.0f) * fast_rcp(t + 1.0f);
}

// 8 lanes per batch element: lane j (j<5) owns hidden unit j.
// h[0..4] broadcast each step via width-8 shuffles. Weight rows for
// gates {r,z,n} of unit j live in ~30 registers per lane.
// 128 n * 8 lanes = 1024 threads = 16 blocks x 64.
__global__ __launch_bounds__(64, 1) void gru_kernel(
    const float* __restrict__ x,      // [N, T, F]
    const float* __restrict__ w_ih,   // [3H, F]
    const float* __restrict__ w_hh,   // [3H, H]
    const float* __restrict__ b_ih,   // [3H]
    const float* __restrict__ b_hh,   // [3H]
    float* __restrict__ states)       // [N, T, H]
{
    const int gid = blockIdx.x * 64 + threadIdx.x;
    const int n = gid >> 3;
    const int j = threadIdx.x & 7;
    const int jj = (j < 5) ? j : 4;   // lanes 5-7 clone unit 4 (results discarded)

    // Per-lane weight rows: r-gate = row jj, z-gate = row 5+jj, n-gate = row 10+jj
    float wir[F_IN], wiz[F_IN], win[F_IN];
    float whr[H_DIM], whz[H_DIM], whn[H_DIM];
#pragma unroll
    for (int f = 0; f < F_IN; ++f) {
        wir[f] = w_ih[(jj)          * F_IN + f];
        wiz[f] = w_ih[(H_DIM + jj)  * F_IN + f];
        win[f] = w_ih[(2*H_DIM + jj)* F_IN + f];
    }
#pragma unroll
    for (int i = 0; i < H_DIM; ++i) {
        whr[i] = w_hh[(jj)          * H_DIM + i];
        whz[i] = w_hh[(H_DIM + jj)  * H_DIM + i];
        whn[i] = w_hh[(2*H_DIM + jj)* H_DIM + i];
    }
    // r/z biases merge (b_ih + b_hh); n-gate biases must stay separate
    // because r multiplies the h-side: n = tanh(i_n + r * h_n).
    const float br  = b_ih[jj]           + b_hh[jj];
    const float bz  = b_ih[H_DIM + jj]   + b_hh[H_DIM + jj];
    const float bin = b_ih[2*H_DIM + jj];
    const float bhn = b_hh[2*H_DIM + jj];

    float h = 0.0f;  // h[j] for this lane

    const float* xp = x + (size_t)n * T_STEPS * F_IN;
    float* sp = states + (size_t)n * T_STEPS * H_DIM;

    for (int t = 0; t < T_STEPS; ++t) {
        const float x0 = xp[t * F_IN + 0];
        const float x1 = xp[t * F_IN + 1];
        const float x2 = xp[t * F_IN + 2];

        const float h0 = __shfl(h, 0, 8);
        const float h1 = __shfl(h, 1, 8);
        const float h2 = __shfl(h, 2, 8);
        const float h3 = __shfl(h, 3, 8);
        const float h4 = __shfl(h, 4, 8);

        // r and z: single fused accumulation (x-side + h-side + merged bias)
        float ar = br + x0*wir[0] + x1*wir[1] + x2*wir[2]
                      + h0*whr[0] + h1*whr[1] + h2*whr[2] + h3*whr[3] + h4*whr[4];
        float az = bz + x0*wiz[0] + x1*wiz[1] + x2*wiz[2]
                      + h0*whz[0] + h1*whz[1] + h2*whz[2] + h3*whz[3] + h4*whz[4];
        // n-gate: keep i_n and h_n separate
        float gin = bin + x0*win[0] + x1*win[1] + x2*win[2];
        float ghn = bhn + h0*whn[0] + h1*whn[1] + h2*whn[2] + h3*whn[3] + h4*whn[4];

        const float r  = fast_sigmoid(ar);
        const float z  = fast_sigmoid(az);
        const float nn = fast_tanh(gin + r * ghn);
        h = (1.0f - z) * nn + z * h;

        if (j < 5) sp[t * H_DIM + j] = h;
    }
}

// Write-BW-bound readout: out[p, o] = exp(dot(states[p,:], lw[o,:]) + lb[o]).
// Thread tid owns neurons [tid*8, tid*8+8): lw/lb preloaded in registers,
// stores as 2x float4 (contiguous 8 KB per block per (n,t) pair).
// p is block-uniform -> state loads compile to scalar loads.
__global__ __launch_bounds__(256) void readout_kernel(
    const float* __restrict__ states, // [NT, H]
    const float* __restrict__ lw,     // [NEURONS, H]
    const float* __restrict__ lb,     // [NEURONS]
    float* __restrict__ out)          // [NT, NEURONS]
{
    const int tid = threadIdx.x;
    const bool active = (tid * 8) < NEURONS;  // tid < 250
    const int o0 = tid * 8;

    float w[8][H_DIM];
    float b[8];
    if (active) {
#pragma unroll
        for (int i = 0; i < 8; ++i) {
            b[i] = lb[o0 + i];
#pragma unroll
            for (int jj = 0; jj < H_DIM; ++jj) w[i][jj] = lw[(o0 + i) * H_DIM + jj];
        }
    }

    for (int p = blockIdx.x; p < NT; p += gridDim.x) {
        const float* hp = states + (size_t)p * H_DIM;
        const float h0 = hp[0], h1 = hp[1], h2 = hp[2], h3 = hp[3], h4 = hp[4];
        if (active) {
            float v[8];
#pragma unroll
            for (int i = 0; i < 8; ++i) {
                float a = b[i] + w[i][0] * h0 + w[i][1] * h1 + w[i][2] * h2 +
                          w[i][3] * h3 + w[i][4] * h4;
                v[i] = __expf(a);
            }
            float4* op = (float4*)(out + (size_t)p * NEURONS + o0);
            op[0] = make_float4(v[0], v[1], v[2], v[3]);
            op[1] = make_float4(v[4], v[5], v[6], v[7]);
        }
    }
}

extern "C" void kernel_launch(void* const* d_in, const int* in_sizes, int n_in,
                              void* d_out, int out_size, void* d_ws, size_t ws_size,
                              hipStream_t stream) {
    const float* x    = (const float*)d_in[0];
    const float* w_ih = (const float*)d_in[1];
    const float* w_hh = (const float*)d_in[2];
    const float* b_ih = (const float*)d_in[3];
    const float* b_hh = (const float*)d_in[4];
    const float* lw   = (const float*)d_in[5];
    const float* lb   = (const float*)d_in[6];
    float* out = (float*)d_out;

    float* states = (float*)d_ws;  // NT * H floats = 1.31 MB

    gru_kernel<<<16, 64, 0, stream>>>(x, w_ih, w_hh, b_ih, b_hh, states);
    readout_kernel<<<2048, 256, 0, stream>>>(states, lw, lb, out);
}

// Round 3
// 634.878 us; speedup vs baseline: 1.0591x; 1.0591x over previous
//
#include <hip/hip_runtime.h>
#include <hip/hip_bf16.h>

#define N_BATCH 128
#define T_STEPS 512
#define F_IN 3
#define H_DIM 5
#define NEURONS 2000
#define NT (N_BATCH * T_STEPS)
#define SROW 8                 // padded state row stride (floats, 32B)
#define XLDS_STRIDE 1540       // 512*3 + 4 pad -> banks (4*nl + 3t)%32, conflict-free

__device__ __forceinline__ float fast_rcp(float x) {
    return __builtin_amdgcn_rcpf(x);
}

__device__ __forceinline__ float fast_sigmoid(float x) {
    return fast_rcp(1.0f + __expf(-x));
}

__device__ __forceinline__ float fast_tanh(float x) {
    float t = __expf(x + x);
    return (t - 1.0f) * fast_rcp(t + 1.0f);
}

// 8 lanes per batch element: lane j (j<5) owns hidden unit j; lanes 5-7 clone
// unit 4 (their outputs fill state-row pad slots, ignored by the readout).
// x staged in LDS up-front; next step's x prefetched from LDS before the
// current step's dependent chain so ds_read latency overlaps compute.
__global__ __launch_bounds__(64, 1) void gru_kernel(
    const float* __restrict__ x,      // [N, T, F]
    const float* __restrict__ w_ih,   // [3H, F]
    const float* __restrict__ w_hh,   // [3H, H]
    const float* __restrict__ b_ih,   // [3H]
    const float* __restrict__ b_hh,   // [3H]
    float* __restrict__ states)       // [NT, SROW]
{
    __shared__ float xs[8 * XLDS_STRIDE];   // 49,280 B

    const int tid = threadIdx.x;
    const int b   = blockIdx.x;

    // Stage this block's 8 batch rows of x (12288 floats, contiguous) into LDS.
    // float4 never crosses an n boundary (1536 % 4 == 0).
    const float* xg = x + (size_t)b * 8 * T_STEPS * F_IN;
    for (int e4 = tid; e4 < (8 * T_STEPS * F_IN) / 4; e4 += 64) {
        float4 v = ((const float4*)xg)[e4];
        int e   = e4 * 4;
        int nl  = e / (T_STEPS * F_IN);
        int off = e - nl * (T_STEPS * F_IN);
        float* d = &xs[nl * XLDS_STRIDE + off];
        d[0] = v.x; d[1] = v.y; d[2] = v.z; d[3] = v.w;
    }
    __syncthreads();

    const int nl = tid >> 3;          // local batch index 0..7
    const int j  = tid & 7;
    const int jj = (j < 5) ? j : 4;

    float wir[F_IN], wiz[F_IN], win[F_IN];
    float whr[H_DIM], whz[H_DIM], whn[H_DIM];
#pragma unroll
    for (int f = 0; f < F_IN; ++f) {
        wir[f] = w_ih[(jj)            * F_IN + f];
        wiz[f] = w_ih[(H_DIM + jj)    * F_IN + f];
        win[f] = w_ih[(2*H_DIM + jj)  * F_IN + f];
    }
#pragma unroll
    for (int i = 0; i < H_DIM; ++i) {
        whr[i] = w_hh[(jj)            * H_DIM + i];
        whz[i] = w_hh[(H_DIM + jj)    * H_DIM + i];
        whn[i] = w_hh[(2*H_DIM + jj)  * H_DIM + i];
    }
    const float br  = b_ih[jj]          + b_hh[jj];
    const float bz  = b_ih[H_DIM + jj]  + b_hh[H_DIM + jj];
    const float bin = b_ih[2*H_DIM + jj];
    const float bhn = b_hh[2*H_DIM + jj];

    const float* xl = &xs[nl * XLDS_STRIDE];
    float* sp = states + (size_t)(b * 8 + nl) * T_STEPS * SROW;

    float h = 0.0f;
    float nx0 = xl[0], nx1 = xl[1], nx2 = xl[2];

    for (int t = 0; t < T_STEPS; ++t) {
        const float x0 = nx0, x1 = nx1, x2 = nx2;
        // Prefetch next step's x from LDS (t=511 reads pad, value unused).
        nx0 = xl[(t + 1) * 3 + 0];
        nx1 = xl[(t + 1) * 3 + 1];
        nx2 = xl[(t + 1) * 3 + 2];

        const float h0 = __shfl(h, 0, 8);
        const float h1 = __shfl(h, 1, 8);
        const float h2 = __shfl(h, 2, 8);
        const float h3 = __shfl(h, 3, 8);
        const float h4 = __shfl(h, 4, 8);

        float ar = br + x0*wir[0] + x1*wir[1] + x2*wir[2]
                      + h0*whr[0] + h1*whr[1] + h2*whr[2] + h3*whr[3] + h4*whr[4];
        float az = bz + x0*wiz[0] + x1*wiz[1] + x2*wiz[2]
                      + h0*whz[0] + h1*whz[1] + h2*whz[2] + h3*whz[3] + h4*whz[4];
        float gin = bin + x0*win[0] + x1*win[1] + x2*win[2];
        float ghn = bhn + h0*whn[0] + h1*whn[1] + h2*whn[2] + h3*whn[3] + h4*whn[4];

        const float r  = fast_sigmoid(ar);
        const float z  = fast_sigmoid(az);
        const float nn = fast_tanh(gin + r * ghn);
        h = (1.0f - z) * nn + z * h;

        sp[t * SROW + j] = h;   // all 8 lanes write: dense 32B per segment
    }
}

// Write-BW-bound readout. Row split into two column halves so every float4
// store instruction is fully wave-contiguous (1 KB/wave, like fillBuffer):
//   half 1: thread tid -> neurons [tid*4, tid*4+4)          (all 256 threads)
//   half 2: thread tid -> neurons [1024 + tid*4, ...)        (tid < 244)
__global__ __launch_bounds__(256) void readout_kernel(
    const float* __restrict__ states, // [NT, SROW]
    const float* __restrict__ lw,     // [NEURONS, H]
    const float* __restrict__ lb,     // [NEURONS]
    float* __restrict__ out)          // [NT, NEURONS]
{
    const int tid = threadIdx.x;
    const int o1 = tid * 4;
    const int o2 = 1024 + tid * 4;
    const bool act2 = o2 < NEURONS;   // tid < 244

    float w1[4][H_DIM], b1[4];
    float w2[4][H_DIM], b2[4];
#pragma unroll
    for (int i = 0; i < 4; ++i) {
        b1[i] = lb[o1 + i];
#pragma unroll
        for (int k = 0; k < H_DIM; ++k) w1[i][k] = lw[(o1 + i) * H_DIM + k];
    }
    if (act2) {
#pragma unroll
        for (int i = 0; i < 4; ++i) {
            b2[i] = lb[o2 + i];
#pragma unroll
            for (int k = 0; k < H_DIM; ++k) w2[i][k] = lw[(o2 + i) * H_DIM + k];
        }
    }

    for (int p = blockIdx.x; p < NT; p += gridDim.x) {
        const float* hp = states + (size_t)p * SROW;
        const float4 hv = *(const float4*)hp;   // 16B-aligned (SROW=8)
        const float h4  = hp[4];

        float* row = out + (size_t)p * NEURONS;

        float4 v1;
        v1.x = __expf(b1[0] + w1[0][0]*hv.x + w1[0][1]*hv.y + w1[0][2]*hv.z + w1[0][3]*hv.w + w1[0][4]*h4);
        v1.y = __expf(b1[1] + w1[1][0]*hv.x + w1[1][1]*hv.y + w1[1][2]*hv.z + w1[1][3]*hv.w + w1[1][4]*h4);
        v1.z = __expf(b1[2] + w1[2][0]*hv.x + w1[2][1]*hv.y + w1[2][2]*hv.z + w1[2][3]*hv.w + w1[2][4]*h4);
        v1.w = __expf(b1[3] + w1[3][0]*hv.x + w1[3][1]*hv.y + w1[3][2]*hv.z + w1[3][3]*hv.w + w1[3][4]*h4);
        ((float4*)row)[tid] = v1;

        if (act2) {
            float4 v2;
            v2.x = __expf(b2[0] + w2[0][0]*hv.x + w2[0][1]*hv.y + w2[0][2]*hv.z + w2[0][3]*hv.w + w2[0][4]*h4);
            v2.y = __expf(b2[1] + w2[1][0]*hv.x + w2[1][1]*hv.y + w2[1][2]*hv.z + w2[1][3]*hv.w + w2[1][4]*h4);
            v2.z = __expf(b2[2] + w2[2][0]*hv.x + w2[2][1]*hv.y + w2[2][2]*hv.z + w2[2][3]*hv.w + w2[2][4]*h4);
            v2.w = __expf(b2[3] + w2[3][0]*hv.x + w2[3][1]*hv.y + w2[3][2]*hv.z + w2[3][3]*hv.w + w2[3][4]*h4);
            *(float4*)(row + o2) = v2;
        }
    }
}

extern "C" void kernel_launch(void* const* d_in, const int* in_sizes, int n_in,
                              void* d_out, int out_size, void* d_ws, size_t ws_size,
                              hipStream_t stream) {
    const float* x    = (const float*)d_in[0];
    const float* w_ih = (const float*)d_in[1];
    const float* w_hh = (const float*)d_in[2];
    const float* b_ih = (const float*)d_in[3];
    const float* b_hh = (const float*)d_in[4];
    const float* lw   = (const float*)d_in[5];
    const float* lb   = (const float*)d_in[6];
    float* out = (float*)d_out;

    float* states = (float*)d_ws;   // NT * SROW * 4 = 2 MB scratch

    gru_kernel<<<16, 64, 0, stream>>>(x, w_ih, w_hh, b_ih, b_hh, states);
    readout_kernel<<<2048, 256, 0, stream>>>(states, lw, lb, out);
}

// Round 4
// 629.931 us; speedup vs baseline: 1.0674x; 1.0079x over previous
//
#include <hip/hip_runtime.h>
#include <hip/hip_bf16.h>

#define N_BATCH 128
#define T_STEPS 512
#define F_IN 3
#define H_DIM 5
#define NEURONS 2000
#define NT (N_BATCH * T_STEPS)
#define SROW 8                 // padded state row stride (floats, 32B)
#define C_STEPS 8              // x prefetch chunk (8 steps = 24 floats = 6 float4)
#define N_CHUNKS (T_STEPS / C_STEPS)   // 64

#define LOG2E  1.44269504088896340736f
#define LOG2E2 2.88539008177792681472f

__device__ __forceinline__ float fast_rcp(float x) {
    return __builtin_amdgcn_rcpf(x);
}

// exp2-based activations; weights pre-scaled so no per-step constant muls.
__device__ __forceinline__ float exp2f_hw(float x) {
    return __builtin_amdgcn_exp2f(x);
}

template <int LANE>
__device__ __forceinline__ float quad_bcast(float v) {
    // DPP quad_perm broadcast of lane LANE within each 4-lane group (VALU-only).
    int i = __builtin_amdgcn_mov_dpp(__float_as_int(v), LANE * 0x55, 0xF, 0xF, false);
    return __int_as_float(i);
}

// GRU: 4 lanes per batch element. Lane k owns hidden unit k; ALL lanes
// redundantly compute unit 4 so h4 is lane-local. h0..h3 broadcast via DPP
// quad_perm. x double-buffered in registers via chunked global float4 loads.
// No LDS / ds_bpermute anywhere in the recurrent loop.
__global__ __launch_bounds__(64, 1) void gru_kernel(
    const float* __restrict__ x,      // [N, T, F]
    const float* __restrict__ w_ih,   // [3H, F]
    const float* __restrict__ w_hh,   // [3H, H]
    const float* __restrict__ b_ih,   // [3H]
    const float* __restrict__ b_hh,   // [3H]
    float* __restrict__ states)       // [NT, SROW]
{
    const int tid = threadIdx.x;
    const int gid = blockIdx.x * 64 + tid;
    const int n   = gid >> 2;     // 0..127   (grid: 8 blocks x 64 = 512 threads)
    const int k   = tid & 3;      // owned unit (unit 4 computed redundantly)

    // ---- weights (registers). r/z gates pre-scaled by log2e, n gate by 2*log2e.
    float wirA[F_IN], wizA[F_IN], winA[F_IN], whrA[H_DIM], whzA[H_DIM], whnA[H_DIM];
    float wirB[F_IN], wizB[F_IN], winB[F_IN], whrB[H_DIM], whzB[H_DIM], whnB[H_DIM];
#pragma unroll
    for (int f = 0; f < F_IN; ++f) {
        wirA[f] = w_ih[(k)            * F_IN + f] * LOG2E;
        wizA[f] = w_ih[(H_DIM + k)    * F_IN + f] * LOG2E;
        winA[f] = w_ih[(2*H_DIM + k)  * F_IN + f] * LOG2E2;
        wirB[f] = w_ih[(4)            * F_IN + f] * LOG2E;
        wizB[f] = w_ih[(H_DIM + 4)    * F_IN + f] * LOG2E;
        winB[f] = w_ih[(2*H_DIM + 4)  * F_IN + f] * LOG2E2;
    }
#pragma unroll
    for (int i = 0; i < H_DIM; ++i) {
        whrA[i] = w_hh[(k)            * H_DIM + i] * LOG2E;
        whzA[i] = w_hh[(H_DIM + k)    * H_DIM + i] * LOG2E;
        whnA[i] = w_hh[(2*H_DIM + k)  * H_DIM + i] * LOG2E2;
        whrB[i] = w_hh[(4)            * H_DIM + i] * LOG2E;
        whzB[i] = w_hh[(H_DIM + 4)    * H_DIM + i] * LOG2E;
        whnB[i] = w_hh[(2*H_DIM + 4)  * H_DIM + i] * LOG2E2;
    }
    const float brA  = (b_ih[k]           + b_hh[k])           * LOG2E;
    const float bzA  = (b_ih[H_DIM + k]   + b_hh[H_DIM + k])   * LOG2E;
    const float binA =  b_ih[2*H_DIM + k]                      * LOG2E2;
    const float bhnA =  b_hh[2*H_DIM + k]                      * LOG2E2;
    const float brB  = (b_ih[4]           + b_hh[4])           * LOG2E;
    const float bzB  = (b_ih[H_DIM + 4]   + b_hh[H_DIM + 4])   * LOG2E;
    const float binB =  b_ih[2*H_DIM + 4]                      * LOG2E2;
    const float bhnB =  b_hh[2*H_DIM + 4]                      * LOG2E2;

    const float* xp = x + (size_t)n * (T_STEPS * F_IN);
    float* sp = states + (size_t)n * T_STEPS * SROW;

    float hA = 0.0f;   // h[k] for this lane
    float hB = 0.0f;   // h[4], lane-local (redundant)

    float xa[3 * C_STEPS], xb[3 * C_STEPS];

#define LOAD_CHUNK(dst, cc)                                            \
    {                                                                  \
        const float4* src = (const float4*)xp + 6 * (cc);              \
        _Pragma("unroll")                                              \
        for (int i = 0; i < 6; ++i) {                                  \
            float4 v = src[i];                                         \
            dst[4*i+0] = v.x; dst[4*i+1] = v.y;                        \
            dst[4*i+2] = v.z; dst[4*i+3] = v.w;                        \
        }                                                              \
    }

#define STEP(xc, t, so)                                                          \
    {                                                                            \
        const float x0 = xc[3*(t)+0], x1 = xc[3*(t)+1], x2 = xc[3*(t)+2];        \
        const float h0 = quad_bcast<0>(hA);                                      \
        const float h1 = quad_bcast<1>(hA);                                      \
        const float h2 = quad_bcast<2>(hA);                                      \
        const float h3 = quad_bcast<3>(hA);                                      \
        const float h4 = hB;                                                     \
        float arA = fmaf(x0,wirA[0], fmaf(x1,wirA[1], fmaf(x2,wirA[2], brA)));   \
        arA = fmaf(h0,whrA[0], fmaf(h1,whrA[1], fmaf(h2,whrA[2],                 \
              fmaf(h3,whrA[3], fmaf(h4,whrA[4], arA)))));                        \
        float azA = fmaf(x0,wizA[0], fmaf(x1,wizA[1], fmaf(x2,wizA[2], bzA)));   \
        azA = fmaf(h0,whzA[0], fmaf(h1,whzA[1], fmaf(h2,whzA[2],                 \
              fmaf(h3,whzA[3], fmaf(h4,whzA[4], azA)))));                        \
        float giA = fmaf(x0,winA[0], fmaf(x1,winA[1], fmaf(x2,winA[2], binA)));  \
        float ghA = fmaf(h0,whnA[0], fmaf(h1,whnA[1], fmaf(h2,whnA[2],           \
              fmaf(h3,whnA[3], fmaf(h4,whnA[4], bhnA)))));                       \
        float arB = fmaf(x0,wirB[0], fmaf(x1,wirB[1], fmaf(x2,wirB[2], brB)));   \
        arB = fmaf(h0,whrB[0], fmaf(h1,whrB[1], fmaf(h2,whrB[2],                 \
              fmaf(h3,whrB[3], fmaf(h4,whrB[4], arB)))));                        \
        float azB = fmaf(x0,wizB[0], fmaf(x1,wizB[1], fmaf(x2,wizB[2], bzB)));   \
        azB = fmaf(h0,whzB[0], fmaf(h1,whzB[1], fmaf(h2,whzB[2],                 \
              fmaf(h3,whzB[3], fmaf(h4,whzB[4], azB)))));                        \
        float giB = fmaf(x0,winB[0], fmaf(x1,winB[1], fmaf(x2,winB[2], binB)));  \
        float ghB = fmaf(h0,whnB[0], fmaf(h1,whnB[1], fmaf(h2,whnB[2],           \
              fmaf(h3,whnB[3], fmaf(h4,whnB[4], bhnB)))));                       \
        const float rA = fast_rcp(1.0f + exp2f_hw(-arA));                        \
        const float zA = fast_rcp(1.0f + exp2f_hw(-azA));                        \
        const float tA = exp2f_hw(fmaf(rA, ghA, giA));                           \
        const float nA = (tA - 1.0f) * fast_rcp(tA + 1.0f);                      \
        hA = fmaf(zA, hA - nA, nA);                                              \
        const float rB = fast_rcp(1.0f + exp2f_hw(-arB));                        \
        const float zB = fast_rcp(1.0f + exp2f_hw(-azB));                        \
        const float tB = exp2f_hw(fmaf(rB, ghB, giB));                           \
        const float nB = (tB - 1.0f) * fast_rcp(tB + 1.0f);                      \
        hB = fmaf(zB, hB - nB, nB);                                              \
        (so)[(t) * SROW + k] = hA;                                               \
        if (k == 0) (so)[(t) * SROW + 4] = hB;                                   \
    }

#define PROC8(xc, so)                                                            \
    {                                                                            \
        STEP(xc, 0, so) STEP(xc, 1, so) STEP(xc, 2, so) STEP(xc, 3, so)          \
        STEP(xc, 4, so) STEP(xc, 5, so) STEP(xc, 6, so) STEP(xc, 7, so)          \
    }

    LOAD_CHUNK(xa, 0)
    LOAD_CHUNK(xb, 1)

    for (int c = 0; c < N_CHUNKS; c += 2) {
        float* soA = sp + (size_t)c * C_STEPS * SROW;
        PROC8(xa, soA)
        {   // prefetch chunk c+2 (clamped reload of 62 at the tail; unused)
            int cc = c + 2; if (cc > N_CHUNKS - 2) cc = N_CHUNKS - 2;
            LOAD_CHUNK(xa, cc)
        }
        float* soB = sp + (size_t)(c + 1) * C_STEPS * SROW;
        PROC8(xb, soB)
        {   // prefetch chunk c+3 (clamped)
            int cc = c + 3; if (cc > N_CHUNKS - 1) cc = N_CHUNKS - 1;
            LOAD_CHUNK(xb, cc)
        }
    }
#undef STEP
#undef PROC8
#undef LOAD_CHUNK
}

// Readout: UNCHANGED from round 3 (controlled experiment — delta attributes
// to the GRU change). out[p,o] = exp(dot(states[p,:], lw[o,:]) + lb[o]).
__global__ __launch_bounds__(256) void readout_kernel(
    const float* __restrict__ states, // [NT, SROW]
    const float* __restrict__ lw,     // [NEURONS, H]
    const float* __restrict__ lb,     // [NEURONS]
    float* __restrict__ out)          // [NT, NEURONS]
{
    const int tid = threadIdx.x;
    const int o1 = tid * 4;
    const int o2 = 1024 + tid * 4;
    const bool act2 = o2 < NEURONS;   // tid < 244

    float w1[4][H_DIM], b1[4];
    float w2[4][H_DIM], b2[4];
#pragma unroll
    for (int i = 0; i < 4; ++i) {
        b1[i] = lb[o1 + i];
#pragma unroll
        for (int kk = 0; kk < H_DIM; ++kk) w1[i][kk] = lw[(o1 + i) * H_DIM + kk];
    }
    if (act2) {
#pragma unroll
        for (int i = 0; i < 4; ++i) {
            b2[i] = lb[o2 + i];
#pragma unroll
            for (int kk = 0; kk < H_DIM; ++kk) w2[i][kk] = lw[(o2 + i) * H_DIM + kk];
        }
    }

    for (int p = blockIdx.x; p < NT; p += gridDim.x) {
        const float* hp = states + (size_t)p * SROW;
        const float4 hv = *(const float4*)hp;   // 16B-aligned (SROW=8)
        const float h4  = hp[4];

        float* row = out + (size_t)p * NEURONS;

        float4 v1;
        v1.x = __expf(b1[0] + w1[0][0]*hv.x + w1[0][1]*hv.y + w1[0][2]*hv.z + w1[0][3]*hv.w + w1[0][4]*h4);
        v1.y = __expf(b1[1] + w1[1][0]*hv.x + w1[1][1]*hv.y + w1[1][2]*hv.z + w1[1][3]*hv.w + w1[1][4]*h4);
        v1.z = __expf(b1[2] + w1[2][0]*hv.x + w1[2][1]*hv.y + w1[2][2]*hv.z + w1[2][3]*hv.w + w1[2][4]*h4);
        v1.w = __expf(b1[3] + w1[3][0]*hv.x + w1[3][1]*hv.y + w1[3][2]*hv.z + w1[3][3]*hv.w + w1[3][4]*h4);
        ((float4*)row)[tid] = v1;

        if (act2) {
            float4 v2;
            v2.x = __expf(b2[0] + w2[0][0]*hv.x + w2[0][1]*hv.y + w2[0][2]*hv.z + w2[0][3]*hv.w + w2[0][4]*h4);
            v2.y = __expf(b2[1] + w2[1][0]*hv.x + w2[1][1]*hv.y + w2[1][2]*hv.z + w2[1][3]*hv.w + w2[1][4]*h4);
            v2.z = __expf(b2[2] + w2[2][0]*hv.x + w2[2][1]*hv.y + w2[2][2]*hv.z + w2[2][3]*hv.w + w2[2][4]*h4);
            v2.w = __expf(b2[3] + w2[3][0]*hv.x + w2[3][1]*hv.y + w2[3][2]*hv.z + w2[3][3]*hv.w + w2[3][4]*h4);
            *(float4*)(row + o2) = v2;
        }
    }
}

extern "C" void kernel_launch(void* const* d_in, const int* in_sizes, int n_in,
                              void* d_out, int out_size, void* d_ws, size_t ws_size,
                              hipStream_t stream) {
    const float* x    = (const float*)d_in[0];
    const float* w_ih = (const float*)d_in[1];
    const float* w_hh = (const float*)d_in[2];
    const float* b_ih = (const float*)d_in[3];
    const float* b_hh = (const float*)d_in[4];
    const float* lw   = (const float*)d_in[5];
    const float* lb   = (const float*)d_in[6];
    float* out = (float*)d_out;

    float* states = (float*)d_ws;   // NT * SROW * 4 = 2 MB scratch

    gru_kernel<<<8, 64, 0, stream>>>(x, w_ih, w_hh, b_ih, b_hh, states);
    readout_kernel<<<2048, 256, 0, stream>>>(states, lw, lb, out);
}